// Round 11
// baseline (776.973 us; speedup 1.0000x reference)
//
#include <hip/hip_runtime.h>
#include <hip/hip_fp16.h>

// B=2048 rows, T=2048 steps, H=32. Wave = ONE batch row; lane = (k, gp).
// gp0 owns gates {i,f}, gp1 owns {g,o} (R8/R10-verified datapath).
// R11 changes vs R10 (which passed but burned ~203 VALU instrs/step):
//  1. Packed weights round-trip through LDS at init (write -> barrier ->
//     read back). ds_read results cannot be cheaply rematerialized, so the
//     32 weight dwords finally stay register-resident instead of being
//     re-built from global every step (R10: VGPR=48, ~128 remat instrs).
//  2. Dot products via v_pk_fma_f16 (__builtin_elementwise_fma on v2h:
//     native clang lowering, no __has_builtin availability gamble like
//     fdot2). 4-deep x 4 chains per gate, f32 combine -> accumulation
//     rounding stays ~5e-4.
//  3. Gather (cvt + permlane16_swap + pack + 15x v_mov_dpp row_ror, probe-
//     calibrated), plswap exchange, split activations, paired stores:
//     byte-identical to R10 (passed, absmax 9.77e-4).

#define Bsz 2048
#define Tsz 2048
#define Hsz 32

typedef _Float16 v2h __attribute__((ext_vector_type(2)));

__device__ __forceinline__ float fast_rcp(float x) { return __builtin_amdgcn_rcpf(x); }
__device__ __forceinline__ float fast_exp2(float x) { return __builtin_amdgcn_exp2f(x); }

__device__ __forceinline__ v2h pkfma16(v2h a, v2h b, v2h c) {
#if __has_builtin(__builtin_elementwise_fma)
    return __builtin_elementwise_fma(a, b, c);
#else
    return a * b + c;   // v_pk_mul_f16 + v_pk_add_f16 (slower, still correct)
#endif
}

__device__ __forceinline__ v2h bch(unsigned u) { return __builtin_bit_cast(v2h, u); }

// xor-32 exchange; r0 = low-half-origin value (all lanes), r1 = high-half.
__device__ __forceinline__ void plswap(float a, float b, float& r0, float& r1) {
#if __has_builtin(__builtin_amdgcn_permlane32_swap)
    auto r = __builtin_amdgcn_permlane32_swap(__float_as_uint(a), __float_as_uint(b),
                                              false, false);
    r0 = __uint_as_float(r[0]);
    r1 = __uint_as_float(r[1]);
#else
    const bool hi = (threadIdx.x & 32) != 0;
    r0 = hi ? __shfl_xor(b, 32) : a;
    r1 = hi ? b : __shfl_xor(a, 32);
#endif
}

// xor-16 exchange on dwords; r0 = bit4==0-origin, r1 = bit4==1-origin.
__device__ __forceinline__ void pl16(unsigned a, unsigned b, unsigned& r0, unsigned& r1) {
#if __has_builtin(__builtin_amdgcn_permlane16_swap)
    auto r = __builtin_amdgcn_permlane16_swap(a, b, false, false);
    r0 = r[0];
    r1 = r[1];
#else
    const bool hi = (threadIdx.x & 16) != 0;
    r0 = hi ? (unsigned)__shfl_xor((int)a, 16) : a;
    r1 = hi ? b : (unsigned)__shfl_xor((int)b, 16);
#endif
}

template <int N>
__device__ __forceinline__ unsigned ror16(unsigned v) {
    if constexpr (N == 0) return v;
    else
        return (unsigned)__builtin_amdgcn_mov_dpp((int)v, 0x120 + N, 0xf, 0xf, false);
}

__device__ __forceinline__ unsigned pkh(float a, float b) {
    unsigned ua = (unsigned)__builtin_bit_cast(unsigned short, (_Float16)a);
    unsigned ub = (unsigned)__builtin_bit_cast(unsigned short, (_Float16)b);
    return ua | (ub << 16);
}

__global__ __launch_bounds__(256, 2) void lstm_fwd_kernel(
    const float* __restrict__ x,      // (B, T)
    const float* __restrict__ w_ih,   // (4H, 1)
    const float* __restrict__ w_hh,   // (4H, H)
    const float* __restrict__ b_ih,   // (4H,)
    const float* __restrict__ b_hh,   // (4H,)
    float* __restrict__ out)          // (B, T*H)
{
    __shared__ unsigned wslab[256 * 32];  // 32 KB: per-thread 32-dword W slab

    const int lane = threadIdx.x & 63;
    const int k    = lane & 31;
    const int gp   = lane >> 5;           // 0: gates {i,f} ; 1: gates {g,o}
    const int wv   = __builtin_amdgcn_readfirstlane((int)(threadIdx.x >> 6));
    const int b    = blockIdx.x * 4 + wv;

    // ---- self-calibration probe (R10-verified): lane-id through the same
    // pipeline as h; pd[d] = (src_lane_lo, src_lane_hi) for runtime dword d.
    unsigned pa, pb;
    pl16((unsigned)lane, (unsigned)lane, pa, pb);
    const unsigned probe0 = (pa & 0xffffu) | (pb << 16);
    unsigned pd[16];
    pd[0]  = probe0;
    pd[1]  = ror16<1>(probe0);   pd[2]  = ror16<2>(probe0);
    pd[3]  = ror16<3>(probe0);   pd[4]  = ror16<4>(probe0);
    pd[5]  = ror16<5>(probe0);   pd[6]  = ror16<6>(probe0);
    pd[7]  = ror16<7>(probe0);   pd[8]  = ror16<8>(probe0);
    pd[9]  = ror16<9>(probe0);   pd[10] = ror16<10>(probe0);
    pd[11] = ror16<11>(probe0);  pd[12] = ror16<12>(probe0);
    pd[13] = ror16<13>(probe0);  pd[14] = ror16<14>(probe0);
    pd[15] = ror16<15>(probe0);

    // ---- pack weights to match the runtime h-dword layout, then round-trip
    // through LDS so the register copies are ds_read-sourced (non-remat-able).
    const int jA = gp * 64 + k, jB = jA + 32;   // i|g row, f|o row
    {
        const float* rA = w_hh + (size_t)jA * Hsz;
        const float* rB = w_hh + (size_t)jB * Hsz;
        unsigned WAi[16], WBi[16];
#pragma unroll
        for (int d = 0; d < 16; ++d) {
            const int ia = (int)(pd[d] & 31u);
            const int ib = (int)((pd[d] >> 16) & 31u);
            WAi[d] = pkh(rA[ia], rA[ib]);
            WBi[d] = pkh(rB[ia], rB[ib]);
        }
        uint4* s = reinterpret_cast<uint4*>(&wslab[threadIdx.x * 32]);
#pragma unroll
        for (int j = 0; j < 4; ++j)
            s[j] = make_uint4(WAi[4 * j], WAi[4 * j + 1], WAi[4 * j + 2], WAi[4 * j + 3]);
#pragma unroll
        for (int j = 0; j < 4; ++j)
            s[4 + j] = make_uint4(WBi[4 * j], WBi[4 * j + 1], WBi[4 * j + 2], WBi[4 * j + 3]);
    }
    __syncthreads();
    unsigned WA[16], WB[16];
    {
        const uint4* s = reinterpret_cast<const uint4*>(&wslab[threadIdx.x * 32]);
#pragma unroll
        for (int j = 0; j < 4; ++j) {
            uint4 q = s[j];
            WA[4 * j] = q.x; WA[4 * j + 1] = q.y; WA[4 * j + 2] = q.z; WA[4 * j + 3] = q.w;
        }
#pragma unroll
        for (int j = 0; j < 4; ++j) {
            uint4 q = s[4 + j];
            WB[4 * j] = q.x; WB[4 * j + 1] = q.y; WB[4 * j + 2] = q.z; WB[4 * j + 3] = q.w;
        }
    }

    const float wiA = w_ih[jA], bsA = b_ih[jA] + b_hh[jA];
    const float wiB = w_ih[jB], bsB = b_ih[jB] + b_hh[jB];

    // unified activation: a1 = A1*rcp(1+exp2(B1*p)) + C1
    // gp0 -> sigmoid(i), gp1 -> tanh(g); second value always sigmoid
    const float B1 = gp ? -2.885390082f : -1.442695041f;
    const float A1 = gp ? 2.0f : 1.0f;
    const float C1 = gp ? -1.0f : 0.0f;

    float c = 0.0f, h = 0.0f, hprev = 0.0f;

    const float* xrow = x + (size_t)b * Tsz;
    float* op = out + (size_t)b * (size_t)(Tsz * Hsz) + gp * 32 + k;

    float xc[8], xn[8];
#pragma unroll
    for (int j = 0; j < 8; ++j) xc[j] = xrow[j];

#pragma unroll 1
    for (int t0 = 0; t0 < Tsz; t0 += 8) {
        const int tn = (t0 + 8 < Tsz) ? (t0 + 8) : t0;  // clamped (dead last)
#pragma unroll
        for (int j = 0; j < 8; ++j) xn[j] = xrow[tn + j];

#pragma unroll
        for (int u = 0; u < 8; ++u) {
            // ---- all-VALU h gather: cvt + pl16 + pack + 15 dpp rotations ----
            const unsigned hbits =
                (unsigned)__builtin_bit_cast(unsigned short, (_Float16)h);
            unsigned ra, rb;
            pl16(hbits, hbits, ra, rb);
            const unsigned D0 = (ra & 0xffffu) | (rb << 16);
            unsigned D[16];
            D[0]  = D0;
            D[1]  = ror16<1>(D0);   D[2]  = ror16<2>(D0);
            D[3]  = ror16<3>(D0);   D[4]  = ror16<4>(D0);
            D[5]  = ror16<5>(D0);   D[6]  = ror16<6>(D0);
            D[7]  = ror16<7>(D0);   D[8]  = ror16<8>(D0);
            D[9]  = ror16<9>(D0);   D[10] = ror16<10>(D0);
            D[11] = ror16<11>(D0);  D[12] = ror16<12>(D0);
            D[13] = ror16<13>(D0);  D[14] = ror16<14>(D0);
            D[15] = ror16<15>(D0);

            // ---- pk_fma_f16 dots: 4-deep x 4 chains per gate ----
            v2h aA0 = {0, 0}, aA1 = {0, 0}, aA2 = {0, 0}, aA3 = {0, 0};
            v2h aB0 = {0, 0}, aB1 = {0, 0}, aB2 = {0, 0}, aB3 = {0, 0};
#pragma unroll
            for (int m = 0; m < 4; ++m) {
                aA0 = pkfma16(bch(D[m]),      bch(WA[m]),      aA0);
                aB0 = pkfma16(bch(D[m]),      bch(WB[m]),      aB0);
                aA1 = pkfma16(bch(D[4 + m]),  bch(WA[4 + m]),  aA1);
                aB1 = pkfma16(bch(D[4 + m]),  bch(WB[4 + m]),  aB1);
                aA2 = pkfma16(bch(D[8 + m]),  bch(WA[8 + m]),  aA2);
                aB2 = pkfma16(bch(D[8 + m]),  bch(WB[8 + m]),  aB2);
                aA3 = pkfma16(bch(D[12 + m]), bch(WA[12 + m]), aA3);
                aB3 = pkfma16(bch(D[12 + m]), bch(WB[12 + m]), aB3);
            }
            const v2h sA = aA0 + aA1, tA = aA2 + aA3;   // v_pk_add_f16
            const v2h sB = aB0 + aB1, tB = aB2 + aB3;
            const float xt = xc[u];
            const float pA = (((float)sA.x + (float)sA.y) +
                              ((float)tA.x + (float)tA.y)) +
                             __fmaf_rn(wiA, xt, bsA);
            const float pB = (((float)sB.x + (float)sB.y) +
                              ((float)tB.x + (float)tB.y)) +
                             __fmaf_rn(wiB, xt, bsB);

            // own-pair activations
            const float a1 = __fmaf_rn(A1, fast_rcp(1.0f + fast_exp2(B1 * pA)), C1);
            const float a2 = fast_rcp(1.0f + fast_exp2(-1.442695041f * pB));

            float i_, g_, f_, o_;
            plswap(a1, a1, i_, g_);   // i_ = sig(i), g_ = tanh(g), all lanes
            plswap(a2, a2, f_, o_);   // f_ = sig(f), o_ = sig(o), all lanes

            c = __fmaf_rn(f_, c, i_ * g_);
            const float th =
                __fmaf_rn(2.0f, fast_rcp(1.0f + fast_exp2(-2.885390082f * c)), -1.0f);
            h = o_ * th;

            if (u & 1) {              // paired store: rows t-1 (gp0), t (gp1)
                *op = gp ? h : hprev;
                op += 64;
            } else {
                hprev = h;
            }
        }
#pragma unroll
        for (int j = 0; j < 8; ++j) xc[j] = xn[j];
    }
}

extern "C" void kernel_launch(void* const* d_in, const int* in_sizes, int n_in,
                              void* d_out, int out_size, void* d_ws, size_t ws_size,
                              hipStream_t stream) {
    const float* x    = (const float*)d_in[0];
    const float* w_ih = (const float*)d_in[1];
    const float* w_hh = (const float*)d_in[2];
    const float* b_ih = (const float*)d_in[3];
    const float* b_hh = (const float*)d_in[4];
    float* out = (float*)d_out;

    dim3 grid(Bsz / 4);   // 512 blocks = 2 per CU -> 2 waves/SIMD
    dim3 block(256);      // 4 waves, each = one batch row (32 k x 2 gate-pairs)
    lstm_fwd_kernel<<<grid, block, 0, stream>>>(x, w_ih, w_hh, b_ih, b_hh, out);
}

// Round 12
// 632.535 us; speedup vs baseline: 1.2283x; 1.2283x over previous
//
#include <hip/hip_runtime.h>
#include <hip/hip_fp16.h>

// B=2048 rows, T=2048 steps, H=32. Wave = ONE batch row; lane = (k, gp).
// gp0 owns gates {i,f}, gp1 owns {g,o} (R8-verified datapath, 606us).
// R12: the per-step ~50-instr weight-remat tax (R8: compiler re-loads f32
// weights + cvt + pack every step) is removed by PRE-PACKING weights into
// d_ws in the exact consumption format with a one-block prep kernel:
//   u32 ws[8 quads][64 lanes][4 dwords]; quad q<4 = row jA, q>=4 = row jB;
//   dword m pairs (W[j][2m], W[j][2m+1]) as f16x2  -> any reload is a
//   coalesced L1-hit dwordx4 with zero ALU, and the asm-laundered register
//   copies (live-set ~90 < 128-cap) have no cheap remat path left.
// Bias/w_ih likewise pre-combined into a float4 per lane.

#define Bsz 2048
#define Tsz 2048
#define Hsz 32

typedef _Float16 v2h __attribute__((ext_vector_type(2)));

__device__ __forceinline__ float fast_rcp(float x) { return __builtin_amdgcn_rcpf(x); }
__device__ __forceinline__ float fast_exp2(float x) { return __builtin_amdgcn_exp2f(x); }

__device__ __forceinline__ float fdot2(unsigned a, unsigned b, float c) {
#if __has_builtin(__builtin_amdgcn_fdot2)
    return __builtin_amdgcn_fdot2(__builtin_bit_cast(v2h, a),
                                  __builtin_bit_cast(v2h, b), c, false);
#else
    v2h av = __builtin_bit_cast(v2h, a), bv = __builtin_bit_cast(v2h, b);
    return __fmaf_rn((float)av.x, (float)bv.x,
                     __fmaf_rn((float)av.y, (float)bv.y, c));
#endif
}

// xor-32 exchange; r0 = low-half-origin value (all lanes), r1 = high-half.
__device__ __forceinline__ void plswap(float a, float b, float& r0, float& r1) {
#if __has_builtin(__builtin_amdgcn_permlane32_swap)
    auto r = __builtin_amdgcn_permlane32_swap(__float_as_uint(a), __float_as_uint(b),
                                              false, false);
    r0 = __uint_as_float(r[0]);
    r1 = __uint_as_float(r[1]);
#else
    const bool hi = (threadIdx.x & 32) != 0;
    r0 = hi ? __shfl_xor(b, 32) : a;
    r1 = hi ? b : __shfl_xor(a, 32);
#endif
}

__device__ __forceinline__ unsigned pkh(float a, float b) {
    unsigned ua = (unsigned)__builtin_bit_cast(unsigned short, (_Float16)a);
    unsigned ub = (unsigned)__builtin_bit_cast(unsigned short, (_Float16)b);
    return ua | (ub << 16);
}

// ---- prep: pack weights + bias into d_ws (one block, 256 threads) ----
__global__ void lstm_prep_kernel(const float* __restrict__ w_ih,
                                 const float* __restrict__ w_hh,
                                 const float* __restrict__ b_ih,
                                 const float* __restrict__ b_hh,
                                 unsigned* __restrict__ ws) {
    const int t = threadIdx.x;
#pragma unroll
    for (int i = t; i < 2048; i += 256) {   // u32 index = q*256 + l*4 + d
        const int q = i >> 8;               // quad 0..7
        const int l = (i >> 2) & 63;        // lane
        const int d = i & 3;                // dword within quad
        const int m = (q & 3) * 4 + d;      // h-pair index 0..15
        const int j = (l >> 5) * 64 + (l & 31) + ((q >> 2) ? 32 : 0);
        ws[i] = pkh(w_hh[j * 32 + 2 * m], w_hh[j * 32 + 2 * m + 1]);
    }
    if (t < 64) {
        const int jA = (t >> 5) * 64 + (t & 31), jB = jA + 32;
        float4 v;
        v.x = w_ih[jA]; v.y = b_ih[jA] + b_hh[jA];
        v.z = w_ih[jB]; v.w = b_ih[jB] + b_hh[jB];
        reinterpret_cast<float4*>(ws + 2048)[t] = v;
    }
}

__global__ __launch_bounds__(256)
__attribute__((amdgpu_waves_per_eu(2, 2)))
void lstm_fwd_kernel(
    const float* __restrict__ x,        // (B, T)
    const unsigned* __restrict__ ws,    // packed weights + bias
    float* __restrict__ out)            // (B, T*H)
{
    __shared__ _Float16 hbuf[4][32];    // one 64B h-line per wave(row)

    const int lane = threadIdx.x & 63;
    const int k    = lane & 31;
    const int gp   = lane >> 5;         // 0: gates {i,f} ; 1: gates {g,o}
    const int wv   = __builtin_amdgcn_readfirstlane((int)(threadIdx.x >> 6));
    const int b    = blockIdx.x * 4 + wv;

    // ---- pre-packed weights: 8 coalesced dwordx4 loads, zero ALU ----
    unsigned WA[16], WB[16];
    {
        const uint4* wq = reinterpret_cast<const uint4*>(ws) + lane;
#pragma unroll
        for (int q = 0; q < 4; ++q) {
            uint4 u = wq[q * 64];
            WA[4 * q] = u.x; WA[4 * q + 1] = u.y; WA[4 * q + 2] = u.z; WA[4 * q + 3] = u.w;
        }
#pragma unroll
        for (int q = 0; q < 4; ++q) {
            uint4 u = wq[(4 + q) * 64];
            WB[4 * q] = u.x; WB[4 * q + 1] = u.y; WB[4 * q + 2] = u.z; WB[4 * q + 3] = u.w;
        }
    }
    // launder: asm-defined values have no remat path; live-set ~90 < 128 cap
    asm volatile("" : "+v"(WA[0]), "+v"(WA[1]), "+v"(WA[2]), "+v"(WA[3]),
                      "+v"(WA[4]), "+v"(WA[5]), "+v"(WA[6]), "+v"(WA[7]));
    asm volatile("" : "+v"(WA[8]), "+v"(WA[9]), "+v"(WA[10]), "+v"(WA[11]),
                      "+v"(WA[12]), "+v"(WA[13]), "+v"(WA[14]), "+v"(WA[15]));
    asm volatile("" : "+v"(WB[0]), "+v"(WB[1]), "+v"(WB[2]), "+v"(WB[3]),
                      "+v"(WB[4]), "+v"(WB[5]), "+v"(WB[6]), "+v"(WB[7]));
    asm volatile("" : "+v"(WB[8]), "+v"(WB[9]), "+v"(WB[10]), "+v"(WB[11]),
                      "+v"(WB[12]), "+v"(WB[13]), "+v"(WB[14]), "+v"(WB[15]));

    const float4 wb = reinterpret_cast<const float4*>(ws + 2048)[lane];
    const float wiA = wb.x, bsA = wb.y, wiB = wb.z, bsB = wb.w;

    // unified activation: a1 = A1*rcp(1+exp2(B1*p)) + C1
    // gp0 -> sigmoid(i), gp1 -> tanh(g); second value always sigmoid
    const float B1 = gp ? -2.885390082f : -1.442695041f;
    const float A1 = gp ? 2.0f : 1.0f;
    const float C1 = gp ? -1.0f : 0.0f;

    float c = 0.0f, h = 0.0f, hprev = 0.0f;
    hbuf[wv][k] = (_Float16)0.0f;       // both halves same addr/value: benign

    const float* xrow = x + (size_t)b * Tsz;
    float* op = out + (size_t)b * (size_t)(Tsz * Hsz) + gp * 32 + k;
    const uint4* hl = reinterpret_cast<const uint4*>(&hbuf[wv][0]);

    float xc[8], xn[8];
#pragma unroll
    for (int j = 0; j < 8; ++j) xc[j] = xrow[j];

#pragma unroll 1
    for (int t0 = 0; t0 < Tsz; t0 += 8) {
        const int tn = (t0 + 8 < Tsz) ? (t0 + 8) : t0;  // clamped (dead last)
#pragma unroll
        for (int j = 0; j < 8; ++j) xn[j] = xrow[tn + j];

#pragma unroll
        for (int u = 0; u < 8; ++u) {
            // previous h: 32 f16 as 4 uniform ds_read_b128 (broadcast, no conflict)
            uint4 q0 = hl[0], q1 = hl[1], q2 = hl[2], q3 = hl[3];
            const unsigned hh[16] = {q0.x, q0.y, q0.z, q0.w,
                                     q1.x, q1.y, q1.z, q1.w,
                                     q2.x, q2.y, q2.z, q2.w,
                                     q3.x, q3.y, q3.z, q3.w};
            const float xt = xc[u];

            // 4 independent 8-deep dot chains (2 per owned gate)
            float sA0 = 0.f, sA1 = 0.f, sB0 = 0.f, sB1 = 0.f;
#pragma unroll
            for (int m = 0; m < 8; ++m) {
                sA0 = fdot2(hh[m], WA[m], sA0);
                sB0 = fdot2(hh[m], WB[m], sB0);
            }
#pragma unroll
            for (int m = 8; m < 16; ++m) {
                sA1 = fdot2(hh[m], WA[m], sA1);
                sB1 = fdot2(hh[m], WB[m], sB1);
            }
            const float pA = (sA0 + sA1) + __fmaf_rn(wiA, xt, bsA);
            const float pB = (sB0 + sB1) + __fmaf_rn(wiB, xt, bsB);

            // own-pair activations
            const float a1 = __fmaf_rn(A1, fast_rcp(1.0f + fast_exp2(B1 * pA)), C1);
            const float a2 = fast_rcp(1.0f + fast_exp2(-1.442695041f * pB));

            float i_, g_, f_, o_;
            plswap(a1, a1, i_, g_);     // i_ = sig(i), g_ = tanh(g), all lanes
            plswap(a2, a2, f_, o_);     // f_ = sig(f), o_ = sig(o), all lanes

            c = __fmaf_rn(f_, c, i_ * g_);
            const float th =
                __fmaf_rn(2.0f, fast_rcp(1.0f + fast_exp2(-2.885390082f * c)), -1.0f);
            h = o_ * th;

            hbuf[wv][k] = (_Float16)h;  // next step's input

            if (u & 1) {                // paired store: rows t-1 (gp0), t (gp1)
                *op = gp ? h : hprev;
                op += 64;
            } else {
                hprev = h;
            }
        }
#pragma unroll
        for (int j = 0; j < 8; ++j) xc[j] = xn[j];
    }
}

extern "C" void kernel_launch(void* const* d_in, const int* in_sizes, int n_in,
                              void* d_out, int out_size, void* d_ws, size_t ws_size,
                              hipStream_t stream) {
    const float* x    = (const float*)d_in[0];
    const float* w_ih = (const float*)d_in[1];
    const float* w_hh = (const float*)d_in[2];
    const float* b_ih = (const float*)d_in[3];
    const float* b_hh = (const float*)d_in[4];
    float* out   = (float*)d_out;
    unsigned* ws = (unsigned*)d_ws;     // needs 9216 B

    lstm_prep_kernel<<<1, 256, 0, stream>>>(w_ih, w_hh, b_ih, b_hh, ws);

    dim3 grid(Bsz / 4);   // 512 blocks = 2 per CU -> 2 waves/SIMD
    dim3 block(256);      // 4 waves, each = one batch row (32 k x 2 gate-pairs)
    lstm_fwd_kernel<<<grid, block, 0, stream>>>(x, ws, out);
}